// Round 1
// baseline (69.159 us; speedup 1.0000x reference)
//
#include <hip/hip_runtime.h>

// CrossAttMultiplexer collapses algebraically:
//   scores[n,i,j] = x[n,i]*s[n,j]*(WQ.WK)/sqrt(d)   (rank-1)
//   alpha = softmax_j(scores)  ->  sum_j alpha[n,i,j] == 1
//   out[n,i] = v[n,i] * sum_j alpha[n,i,j] = s[n,i] * WV[0,0]
// So the whole op is out = s * WV. Pure elementwise, memory-bound.

__global__ __launch_bounds__(256) void scale_kernel(
    const float4* __restrict__ s, const float* __restrict__ wv,
    float4* __restrict__ out, int n4) {
    const float w = *wv;  // wave-uniform scalar, L2-broadcast
    int i = blockIdx.x * blockDim.x + threadIdx.x;
    if (i < n4) {
        float4 v = s[i];
        v.x *= w; v.y *= w; v.z *= w; v.w *= w;
        out[i] = v;
    }
}

extern "C" void kernel_launch(void* const* d_in, const int* in_sizes, int n_in,
                              void* d_out, int out_size, void* d_ws, size_t ws_size,
                              hipStream_t stream) {
    // inputs: 0=x, 1=s, 2=WQ, 3=WK, 4=WV (all float32)
    const float4* s  = (const float4*)d_in[1];
    const float*  wv = (const float*)d_in[4];
    float* out = (float*)d_out;

    const int n  = out_size;       // 4*64*64*96 = 1,572,864 (divisible by 4)
    const int n4 = n >> 2;         // 393,216
    const int block = 256;
    const int grid = (n4 + block - 1) / block;  // 1536 blocks
    scale_kernel<<<grid, block, 0, stream>>>(s, wv, (float4*)out, n4);
}